// Round 10
// baseline (461.952 us; speedup 1.0000x reference)
//
#include <hip/hip_runtime.h>

#define N_NODES 50000
#define N_EDGES 800000
#define K_BR    8
#define BCAP    131072           // per-bucket slot capacity (2^17); mean fill 100K
#define MLP_SLOTS (K_BR * BCAP)  // 1,048,576
#define SCAN_BLOCKS 196          // ceil(50000/256)
#define BSTRIDE 1024             // bucketCur stride in ints (R1: null, kept)
#define EPT 8                    // pass1 edges/thread (R3 structure)
#define P1_BLOCKS 391            // ceil(800000 / 2048)
#define RB 128                   // rank blocks
#define RBE 6250                 // edges per rank block (128*6250 = 800000 exactly)
#define REPS 8                   // R10 amplification factor

// R10: MEASUREMENT ROUND (amplification probe). R8/R9 "safe win" bundles netted
// ~0 => rank/cscan/agg are small; the ~94us pipeline concentrates in pass1+mlp,
// never directly observed (top-5 saturated by five 42us poison fills).
// rank/pass1/mlp bodies now loop REPS=8x: rep 0 = exact real behavior (real
// outputs); reps 1-7 rotate indices (kills CSE, same statistics) and write to
// in-workspace scratch with masked indices. Each amplified dispatch ~8x unit
// time > 42us -> surfaces in top-5. unit = shown/8. Residual = cscan+agg+ovh.

typedef _Float16 h2 __attribute__((ext_vector_type(2)));
typedef _Float16 half8 __attribute__((ext_vector_type(8)));
typedef float f32x4 __attribute__((ext_vector_type(4)));

#define MFMA(a, b, c) __builtin_amdgcn_mfma_f32_16x16x32_f16((a), (b), (c), 0, 0, 0)

#define VAL_MASK 0x3FFFFFFFu
#define FLG_A    0x40000000u
#define FLG_P    0x80000000u

// ---------------- workspace layout (bytes) ----------------
// fbuf      : 800,000 x 64 B f16         @ 0           (51,200,000)
// payload   : MLP_SLOTS x 16 B           @ 51,200,000  (16,777,216)
// cnt(deg)  : N ints                     @ 67,977,216  (200,000)
// bucketCur : 8 ints @ 4KB stride        @ 68,177,216  (32,768)   [zeroed by rank b0]
// ps        : 196 uints (lookback)       @ 68,209,984  (800)      [zeroed by rank b0]
// nodeStart : N ints                     @ 68,210,816  (200,000)
// w1f4      : 2048 uint4 (B-frags L1)    @ 68,410,816  (32,768)
// w2f4      : 1024 uint4 (B-frags L2)    @ 68,443,584  (16,384)
// xh        : 50,000 x 32 f16            @ 68,459,968  (3,200,000)
// rankB     : E u16                      @ 71,659,968  (1,600,000)
// cntM      : [128][50000] u8            @ 73,259,968  (6,400,000)
// blkBase   : [128][50000] u16           @ 86,059,968  (12,800,000)
// --- R10 scratch (reps 1-7 sinks) ---
// payloadS  : 16,777,216                 @ 98,859,968
// fbufS     : 33,554,432 (512K x 64B)    @ 115,637,184
// bucketCurS: 32,768                     @ 149,191,616
// rankBS    : 1,600,000                  @ 149,224,384
// cntMS     : 6,400,000                  @ 150,824,384
// xhS       : 3,200,000                  @ 157,224,384
// end 160,424,384 < ws (~268MB per fill size)

__device__ __forceinline__ int branch_idx(float dx, float dy) {
    return (dx > 0.0f ? 1 : 0) + (dy > 0.0f ? 2 : 0) +
           ((fabsf(dx) - fabsf(dy)) > 0.0f ? 4 : 0);
}

__device__ __forceinline__ unsigned pk_f16pair(float a, float b) {
    h2 p; p.x = (_Float16)a; p.y = (_Float16)b;
    return __builtin_bit_cast(unsigned, p);
}

__device__ __forceinline__ unsigned short f16bits(float a) {
    _Float16 h = (_Float16)a;
    return __builtin_bit_cast(unsigned short, h);
}

// Per-block node histogram + per-edge rank. R10: REPS x amplified.
__global__ void __launch_bounds__(512) rank_kernel(
    const int* __restrict__ ei, const float* __restrict__ x,
    const float* __restrict__ W1, const float* __restrict__ W2,
    unsigned short* __restrict__ rankB, unsigned char* __restrict__ cntM,
    unsigned* __restrict__ xh, uint4* __restrict__ w1f4, uint4* __restrict__ w2f4,
    int* __restrict__ bucketCur, unsigned* __restrict__ ps,
    unsigned short* __restrict__ rankBS, unsigned char* __restrict__ cntMS,
    unsigned* __restrict__ xhS) {
    __shared__ unsigned hist[N_NODES / 4];   // 50,000 B
    int t = threadIdx.x, b = blockIdx.x;

    if (b == 0) {                            // absorbed memset (once)
        if (t < K_BR) bucketCur[t * BSTRIDE] = 0;
        if (t < SCAN_BLOCKS) ps[t] = 0;
    }

    // W fragments (once; global tid < 3072)
    int tid = b * 512 + t;
    if (tid < 2048) {                         // layer-1 B frags
        int L = tid & 63, fl = tid >> 6;
        int nt = fl & 1, kt = (fl >> 1) & 1, k = fl >> 2;
        int quad = L >> 4, col = L & 15;
        unsigned dw[4];
#pragma unroll
        for (int i = 0; i < 4; ++i) {
            float v0 = 0.0f, v1 = 0.0f;
            int k0 = kt * 32 + quad * 8 + 2 * i;
            if (k0 < 36)     v0 = W1[k * 1152 + k0 * 32 + nt * 16 + col];
            if (k0 + 1 < 36) v1 = W1[k * 1152 + (k0 + 1) * 32 + nt * 16 + col];
            dw[i] = pk_f16pair(v0, v1);
        }
        w1f4[tid] = make_uint4(dw[0], dw[1], dw[2], dw[3]);
    } else if (tid < 3072) {                  // layer-2 B frags
        int u2 = tid - 2048;
        int L = u2 & 63, fl = u2 >> 6;
        int nt = fl & 1, k = fl >> 1;
        int quad = L >> 4, col = L & 15;
        unsigned dw[4];
#pragma unroll
        for (int i = 0; i < 4; ++i) {
            int k0 = quad * 8 + 2 * i;
            dw[i] = pk_f16pair(W2[k * 1024 + k0 * 32 + nt * 16 + col],
                               W2[k * 1024 + (k0 + 1) * 32 + nt * 16 + col]);
        }
        w2f4[u2] = make_uint4(dw[0], dw[1], dw[2], dw[3]);
    }

    int eb = b * RBE;
    for (int rep = 0; rep < REPS; ++rep) {
        unsigned short* rB = rep ? rankBS : rankB;
        unsigned* xhd      = rep ? xhS : xh;
        unsigned char* cM  = rep ? cntMS : cntM;
        int eSh = rep * 99991;
        for (int i = t; i < N_NODES / 4; i += 512) hist[i] = 0;
        __syncthreads();
        for (int it = 0; it < (RBE + 511) / 512; ++it) {
            int r = it * 512 + t;
            if (r < RBE) {
                int e = eb + r + eSh; if (e >= N_EDGES) e -= N_EDGES;
                int d = ei[N_EDGES + e];
                unsigned sh = (unsigned)(d & 3) * 8u;
                unsigned old = atomicAdd(&hist[d >> 2], 1u << sh);
                rB[e] = (unsigned short)((old >> sh) & 0xFFu);
                float2 xv = ((const float2*)x)[e];
                xhd[e] = pk_f16pair(xv.x, xv.y);
            }
        }
        __syncthreads();
        unsigned* cm = (unsigned*)(cM + (size_t)b * N_NODES);
        for (int i = t; i < N_NODES / 4; i += 512) cm[i] = hist[i];
        __syncthreads();
    }
}

// Fused column-scan + decoupled-lookback scan (unchanged from R9).
__global__ void cscan_kernel(const unsigned char* __restrict__ cntM,
                             unsigned short* __restrict__ blkBase,
                             int* __restrict__ cnt, unsigned* __restrict__ ps,
                             int* __restrict__ nodeStart) {
    __shared__ unsigned char cmLds[RB * 256];  // 32,768 B
    __shared__ int s[256];
    __shared__ int sh_off;
    int t = threadIdx.x, b = blockIdx.x;
    int d0 = b * 256;
    int d = d0 + t;
#pragma unroll
    for (int it = 0; it < RB / 4; ++it) {
        int i = it * 256 + t;
        int row = i >> 6;
        int w = i & 63;
        ((unsigned*)cmLds)[row * 64 + w] =
            *(const unsigned*)(cntM + (size_t)row * N_NODES + d0 + (w << 2));
    }
    __syncthreads();
    int acc = 0;
    if (d < N_NODES) {
#pragma unroll 8
        for (int blk = 0; blk < RB; ++blk) {
            int v = cmLds[blk * 256 + t];
            blkBase[(size_t)blk * N_NODES + d] = (unsigned short)acc;
            acc += v;
        }
        cnt[d] = acc;
    }
    int v = (d < N_NODES) ? acc : 0;
    s[t] = v;
    __syncthreads();
#pragma unroll
    for (int off = 1; off < 256; off <<= 1) {
        int tmp = (t >= off) ? s[t - off] : 0;
        __syncthreads();
        s[t] += tmp;
        __syncthreads();
    }
    int excl = s[t] - v;
    if (t == 255)
        atomicExch(&ps[b], (unsigned)s[255] | (b == 0 ? FLG_P : FLG_A));
    if (t == 0) sh_off = 0;
    if (t < 64 && b > 0) {
        int off = 0;
        int base = b - 1;
        for (;;) {
            int idx = base - t;
            unsigned w = 0;
            if (idx >= 0) {
                do { w = atomicOr(&ps[idx], 0u); } while (!(w & (FLG_A | FLG_P)));
            }
            bool isP = (w & FLG_P) != 0;
            unsigned long long pm = __ballot(isP);
            int firstP = pm ? (__ffsll((unsigned long long)pm) - 1) : 64;
            int contrib = (idx >= 0 && t <= firstP) ? (int)(w & VAL_MASK) : 0;
#pragma unroll
            for (int sh = 32; sh > 0; sh >>= 1) contrib += __shfl_down(contrib, sh, 64);
            contrib = __shfl(contrib, 0, 64);
            off += contrib;
            if (firstP < 64 || base - 64 < 0) break;
            base -= 64;
        }
        if (t == 0) sh_off = off;
    }
    __syncthreads();
    if (d < N_NODES) nodeStart[d] = excl + sh_off;
}

// Edge pass. R10: REPS x amplified (rep0 real, reps to scratch, masked idx).
__global__ void pass1_kernel(const int* __restrict__ ei, const float* __restrict__ pos,
                             const float* __restrict__ ea, const float* __restrict__ ew,
                             const unsigned short* __restrict__ rankB,
                             const unsigned short* __restrict__ blkBase,
                             int* __restrict__ bucketCur,
                             uint4* __restrict__ payload,
                             int* __restrict__ bucketCurS,
                             uint4* __restrict__ payloadS) {
    __shared__ int h[K_BR];
    __shared__ int base[K_BR];
    int t = threadIdx.x;
    int eBase = blockIdx.x * (256 * EPT);

    for (int rep = 0; rep < REPS; ++rep) {
        int eSh = rep * 99991;
        int* bc = rep ? bucketCurS : bucketCur;
        uint4* pp = rep ? payloadS : payload;
        unsigned msk = rep ? (unsigned)(MLP_SLOTS - 1) : 0xFFFFFFFFu;
        if (t < K_BR) h[t] = 0;
        __syncthreads();

        int sA[EPT], dA[EPT], krA[EPT], slA[EPT];
#pragma unroll
        for (int it = 0; it < EPT; ++it) {
            int e0 = eBase + it * 256 + t;
            int e = e0 + eSh; if (e >= N_EDGES) e -= N_EDGES;
            int s = 0, d = 0, k = 0, rank = 0, slot = 0;
            if (e0 < N_EDGES) {
                s = ei[e]; d = ei[N_EDGES + e];
                float2 ps2 = ((const float2*)pos)[s];
                float2 pd2 = ((const float2*)pos)[d];
                k = branch_idx(ps2.x - pd2.x, ps2.y - pd2.y);
                rank = atomicAdd(&h[k], 1);
                int bb = e / RBE;
                slot = (int)blkBase[(size_t)bb * N_NODES + d] + (int)rankB[e];
            }
            sA[it] = s; dA[it] = d; krA[it] = (k << 16) | rank; slA[it] = slot;
        }
        __syncthreads();
        if (t < K_BR) base[t] = (h[t] > 0) ? atomicAdd(&bc[t * BSTRIDE], h[t]) : 0;
        __syncthreads();
#pragma unroll
        for (int it = 0; it < EPT; ++it) {
            int e0 = eBase + it * 256 + t;
            int e = e0 + eSh; if (e >= N_EDGES) e -= N_EDGES;
            if (e0 < N_EDGES) {
                int k = krA[it] >> 16, rank = krA[it] & 0xFFFF;
                float4 eav = ((const float4*)ea)[e];
                unsigned ewh = (unsigned)f16bits(ew[e]);
                int idx = (int)(((unsigned)((k << 17) + base[k] + rank)) & msk);
                pp[idx] = make_uint4((unsigned)sA[it] | ((unsigned)dA[it] << 16),
                                     (unsigned)slA[it] | (ewh << 16),
                                     pk_f16pair(eav.x, eav.y),
                                     pk_f16pair(eav.z, eav.w));
            }
        }
        __syncthreads();
    }
}

// R7 MFMA MLP. R10: REPS x amplified (rep0 real; reps rotate rel, store fbufS).
__global__ void __launch_bounds__(128, 4) mlp_kernel(
    const uint4* __restrict__ payload,
    const unsigned* __restrict__ xh,
    const uint4* __restrict__ w1f4, const float* __restrict__ b1,
    const uint4* __restrict__ w2f4, const float* __restrict__ b2,
    const int* __restrict__ nodeStart,
    const int* __restrict__ bucketFill,
    unsigned short* __restrict__ fbuf,
    unsigned short* __restrict__ fbufS) {
    __shared__ uint4 lds4[164];
    char* hreg = (char*)lds4 + (threadIdx.x >> 6) * 1312;

    int t = blockIdx.x * 128 + threadIdx.x;
    int u = __builtin_amdgcn_readfirstlane(t);
    int k = u >> 17;
    int fill = bucketFill[k * BSTRIDE];
    if ((u & (BCAP - 1)) >= fill) return;   // whole wave past bucket fill
    int rel = t & (BCAP - 1);

    int L = threadIdx.x & 63;
    int quad = L >> 4, col = L & 15;

    // B fragments + biases (rep-invariant)
    half8 B1[2][2], B2[2];
#pragma unroll
    for (int kt = 0; kt < 2; ++kt)
#pragma unroll
        for (int nt = 0; nt < 2; ++nt)
            B1[kt][nt] = __builtin_bit_cast(half8, w1f4[((k * 2 + kt) * 2 + nt) * 64 + L]);
#pragma unroll
    for (int nt = 0; nt < 2; ++nt)
        B2[nt] = __builtin_bit_cast(half8, w2f4[(k * 2 + nt) * 64 + L]);
    float b1o0 = b1[k * 32 + col],      b1o1 = b1[k * 32 + 16 + col];
    float b2o0 = b2[k * 32 + col],      b2o1 = b2[k * 32 + 16 + col];

    for (int rep = 0; rep < REPS; ++rep) {
        int rel2 = (rel + rep * 16381) & (BCAP - 1);
        bool valid = rel2 < fill;
        int idx = (k << 17) + min(rel2, fill - 1);
        unsigned short* fb = rep ? fbufS : fbuf;

        uint4 pl = payload[idx];
        int s = (int)(pl.x & 0xFFFFu);
        int d = (int)(pl.x >> 16);
        float whf = (float)__builtin_bit_cast(_Float16, (unsigned short)(pl.y >> 16));
        int slot = valid ? (nodeStart[d] + (int)(pl.y & 0xFFFFu)) : 0;
        if (rep) slot &= 0x7FFFF;
        int vld = valid ? 1 : 0;

#pragma unroll
        for (int mt = 0; mt < 4; ++mt) {
            int erA = mt * 16 + col;
            int sA = __shfl(s, erA, 64);
            int dAi = __shfl(d, erA, 64);
            unsigned zA = (unsigned)__shfl((int)pl.z, erA, 64);
            unsigned wA = (unsigned)__shfl((int)pl.w, erA, 64);
            uint4 xjv = ((const uint4*)xh)[4 * (size_t)sA + quad];
            uint4 xiv = ((const uint4*)xh)[4 * (size_t)dAi + quad];
            half8 a0 = __builtin_bit_cast(half8, xjv) - __builtin_bit_cast(half8, xiv);
            uint4 a1u = make_uint4(quad == 0 ? zA : 0u, quad == 0 ? wA : 0u, 0u, 0u);
            half8 a1 = __builtin_bit_cast(half8, a1u);

            f32x4 c0 = {b1o0, b1o0, b1o0, b1o0};
            f32x4 c1 = {b1o1, b1o1, b1o1, b1o1};
            c0 = MFMA(a0, B1[0][0], c0);
            c0 = MFMA(a1, B1[1][0], c0);
            c1 = MFMA(a0, B1[0][1], c1);
            c1 = MFMA(a1, B1[1][1], c1);
#pragma unroll
            for (int r = 0; r < 4; ++r) {
                int er = quad * 4 + r;
                *(unsigned short*)(hreg + er * 80 + col * 2)        = f16bits(fmaxf(c0[r], 0.0f));
                *(unsigned short*)(hreg + er * 80 + (16 + col) * 2) = f16bits(fmaxf(c1[r], 0.0f));
            }
            half8 ah = __builtin_bit_cast(half8, *(const uint4*)(hreg + col * 80 + quad * 16));
            f32x4 d0 = {b2o0, b2o0, b2o0, b2o0};
            f32x4 d1 = {b2o1, b2o1, b2o1, b2o1};
            d0 = MFMA(ah, B2[0], d0);
            d1 = MFMA(ah, B2[1], d1);
#pragma unroll
            for (int r = 0; r < 4; ++r) {
                int erC = mt * 16 + quad * 4 + r;
                int slC = __shfl(slot, erC, 64);
                float wC = __shfl(whf, erC, 64);
                int vC = __shfl(vld, erC, 64);
                unsigned short v0 = f16bits(fmaxf(d0[r], 0.0f) * wC);
                unsigned short v1 = f16bits(fmaxf(d1[r], 0.0f) * wC);
                if (vC) {
                    unsigned short* orow = fb + 32 * (size_t)slC;
                    orow[col] = v0;
                    orow[16 + col] = v1;
                }
            }
        }
    }
}

// R9 agg: one wave per node (unchanged).
__global__ void agg_kernel(const unsigned short* __restrict__ fbuf,
                           const int* __restrict__ nodeStart, const int* __restrict__ deg,
                           const float* __restrict__ x, const float* __restrict__ Wr,
                           const float* __restrict__ br, float* __restrict__ out) {
    int gw = (blockIdx.x * blockDim.x + threadIdx.x) >> 6;
    if (gw >= N_NODES) return;
    int l = threadIdx.x & 63;
    int q = l >> 4, cp = l & 15;
    int st = nodeStart[gw], dg = deg[gw];
    float a0 = 0.0f, a1 = 0.0f;
    for (int j = q; j < dg; j += 4) {
        unsigned uu = *(const unsigned*)(fbuf + (size_t)(st + j) * 32 + 2 * cp);
        h2 p = __builtin_bit_cast(h2, uu);
        a0 += (float)p.x;
        a1 += (float)p.y;
    }
    float inv = 1.0f / (float)max(dg, 1);
    int c0 = 2 * cp;
    float p0 = a0 * inv + (q == 0 ? br[c0] : 0.0f);
    float p1 = a1 * inv + (q == 0 ? br[c0 + 1] : 0.0f);
    const float* xr = x + 32 * (size_t)gw + q * 8;
#pragma unroll
    for (int kk = 0; kk < 8; ++kk) {
        float xv = xr[kk];
        p0 = fmaf(xv, Wr[(q * 8 + kk) * 32 + c0], p0);
        p1 = fmaf(xv, Wr[(q * 8 + kk) * 32 + c0 + 1], p1);
    }
    p0 += __shfl_xor(p0, 16, 64);
    p0 += __shfl_xor(p0, 32, 64);
    p1 += __shfl_xor(p1, 16, 64);
    p1 += __shfl_xor(p1, 32, 64);
    if (q == 0) {
        float2 o = make_float2(p0, p1);
        *(float2*)(out + 32 * (size_t)gw + c0) = o;
    }
}

extern "C" void kernel_launch(void* const* d_in, const int* in_sizes, int n_in,
                              void* d_out, int out_size, void* d_ws, size_t ws_size,
                              hipStream_t stream) {
    const float* x   = (const float*)d_in[0];
    const float* pos = (const float*)d_in[1];
    const int*   ei  = (const int*)d_in[2];
    const float* ea  = (const float*)d_in[3];
    const float* ew  = (const float*)d_in[4];
    const float* W1  = (const float*)d_in[5];
    const float* b1  = (const float*)d_in[6];
    const float* W2  = (const float*)d_in[7];
    const float* b2  = (const float*)d_in[8];
    const float* Wr  = (const float*)d_in[9];
    const float* br  = (const float*)d_in[10];
    float* out = (float*)d_out;

    char* ws = (char*)d_ws;
    unsigned short* fbuf = (unsigned short*)(ws + 0);
    uint4* payload  = (uint4*)(ws + 51200000);
    int* cnt        = (int*)(ws + 67977216);
    int* bucketCur  = (int*)(ws + 68177216);
    unsigned* psLb  = (unsigned*)(ws + 68209984);
    int* nodeStart  = (int*)(ws + 68210816);
    uint4* w1f4     = (uint4*)(ws + 68410816);
    uint4* w2f4     = (uint4*)(ws + 68443584);
    unsigned* xh    = (unsigned*)(ws + 68459968);
    unsigned short* rankB = (unsigned short*)(ws + 71659968);
    unsigned char* cntM   = (unsigned char*)(ws + 73259968);
    unsigned short* blkBase = (unsigned short*)(ws + 86059968);
    // R10 scratch
    uint4* payloadS = (uint4*)(ws + 98859968);
    unsigned short* fbufS = (unsigned short*)(ws + 115637184);
    int* bucketCurS = (int*)(ws + 149191616);
    unsigned short* rankBS = (unsigned short*)(ws + 149224384);
    unsigned char* cntMS   = (unsigned char*)(ws + 150824384);
    unsigned* xhS   = (unsigned*)(ws + 157224384);

    rank_kernel<<<RB, 512, 0, stream>>>(ei, x, W1, W2, rankB, cntM, xh, w1f4, w2f4,
                                        bucketCur, psLb, rankBS, cntMS, xhS);
    cscan_kernel<<<SCAN_BLOCKS, 256, 0, stream>>>(cntM, blkBase, cnt, psLb, nodeStart);
    pass1_kernel<<<P1_BLOCKS, 256, 0, stream>>>(ei, pos, ea, ew, rankB, blkBase,
                                                bucketCur, payload, bucketCurS, payloadS);
    mlp_kernel<<<MLP_SLOTS / 128, 128, 0, stream>>>(payload, xh, w1f4, b1, w2f4, b2,
                                                    nodeStart, bucketCur, fbuf, fbufS);
    agg_kernel<<<(N_NODES * 64) / 256, 256, 0, stream>>>(fbuf, nodeStart, cnt,
                                                         x, Wr, br, out);
}

// Round 11
// 384.165 us; speedup vs baseline: 1.2025x; 1.2025x over previous
//
#include <hip/hip_runtime.h>

#define N_NODES 50000
#define N_EDGES 800000
#define K_BR    8
#define BCAP    131072           // per-bucket slot capacity (2^17); mean fill 100K
#define MLP_SLOTS (K_BR * BCAP)  // 1,048,576
#define SCAN_BLOCKS 196          // ceil(50000/256)
#define BSTRIDE 1024             // bucketCur stride in ints (R1: null, kept)
#define EPT 8                    // pass1 edges/thread (R3 structure)
#define P1_BLOCKS 391            // ceil(800000 / 2048)
#define RB 128                   // rank blocks
#define RBE 6250                 // edges per rank block (128*6250 = 800000 exactly)
#define REPS 8                   // R11 amplification (cscan+agg only)

// R10 results: mlp_u ~20.9us; rank_u+pass1_u ~18.5 combined. Pipeline ~94us
// => cscan+agg+gaps ~55us, but roofline models say cscan+agg ~15-18. R11:
// amplify cscan+agg (rank/pass1/mlp reverted to clean) to resolve the split.
// Plus one contained mlp opt: INTERLEAVED CHANNEL PACKING — W1/W2 B-frags
// packed so MFMA tile nt covers channels {2c+nt} -> lane col holds adjacent
// channels (2col,2col+1): h-LDS store, fbuf store, bias loads become single
// u32 ops (store instr count halves, 64B-contiguous quarter stores). agg
// already consumes channel pairs as u32 -> plain order preserved end-to-end.

typedef _Float16 h2 __attribute__((ext_vector_type(2)));
typedef _Float16 half8 __attribute__((ext_vector_type(8)));
typedef float f32x4 __attribute__((ext_vector_type(4)));

#define MFMA(a, b, c) __builtin_amdgcn_mfma_f32_16x16x32_f16((a), (b), (c), 0, 0, 0)

#define VAL_MASK 0x3FFFFFFFu
#define FLG_A    0x40000000u
#define FLG_P    0x80000000u

// ---------------- workspace layout (bytes) ----------------
// fbuf      : 800,000 x 64 B f16         @ 0           (51,200,000)
// payload   : MLP_SLOTS x 16 B           @ 51,200,000  (16,777,216)
// cnt(deg)  : N ints                     @ 67,977,216  (200,000)
// bucketCur : 8 ints @ 4KB stride        @ 68,177,216  (32,768)   [zeroed by rank b0]
// ps        : 196 uints (lookback)       @ 68,209,984  (800)      [zeroed by rank b0]
// nodeStart : N ints                     @ 68,210,816  (200,000)
// w1f4      : 2048 uint4 (B-frags L1)    @ 68,410,816  (32,768)
// w2f4      : 1024 uint4 (B-frags L2)    @ 68,443,584  (16,384)
// xh        : 50,000 x 32 f16            @ 68,459,968  (3,200,000)
// rankB     : E u16                      @ 71,659,968  (1,600,000)
// cntM      : [128][50000] u8            @ 73,259,968  (6,400,000)
// blkBase   : [128][50000] u16           @ 86,059,968  (12,800,000)
// --- R11 scratch (cscan/agg reps 1-7 sinks) ---
// blkBaseS  : 12,800,000                 @ 98,859,968
// outS      : 6,400,000                  @ 111,659,968
// end 118,059,968 < ws (~268MB)

__device__ __forceinline__ int branch_idx(float dx, float dy) {
    return (dx > 0.0f ? 1 : 0) + (dy > 0.0f ? 2 : 0) +
           ((fabsf(dx) - fabsf(dy)) > 0.0f ? 4 : 0);
}

__device__ __forceinline__ unsigned pk_f16pair(float a, float b) {
    h2 p; p.x = (_Float16)a; p.y = (_Float16)b;
    return __builtin_bit_cast(unsigned, p);
}

__device__ __forceinline__ unsigned short f16bits(float a) {
    _Float16 h = (_Float16)a;
    return __builtin_bit_cast(unsigned short, h);
}

// Per-block node histogram + per-edge rank (R9 clean form).
// R11: W-frag packing uses interleaved channel map ch = 2*col + nt.
__global__ void __launch_bounds__(512) rank_kernel(
    const int* __restrict__ ei, const float* __restrict__ x,
    const float* __restrict__ W1, const float* __restrict__ W2,
    unsigned short* __restrict__ rankB, unsigned char* __restrict__ cntM,
    unsigned* __restrict__ xh, uint4* __restrict__ w1f4, uint4* __restrict__ w2f4,
    int* __restrict__ bucketCur, unsigned* __restrict__ ps) {
    __shared__ unsigned hist[N_NODES / 4];   // 50,000 B
    int t = threadIdx.x, b = blockIdx.x;
    for (int i = t; i < N_NODES / 4; i += 512) hist[i] = 0;

    if (b == 0) {                            // absorbed memset
        if (t < K_BR) bucketCur[t * BSTRIDE] = 0;
        if (t < SCAN_BLOCKS) ps[t] = 0;
    }

    // W fragments (global tid < 3072); channel map ch = 2*col + nt
    int tid = b * 512 + t;
    if (tid < 2048) {                         // layer-1 B frags
        int L = tid & 63, fl = tid >> 6;
        int nt = fl & 1, kt = (fl >> 1) & 1, k = fl >> 2;
        int quad = L >> 4, col = L & 15;
        int ch = 2 * col + nt;
        unsigned dw[4];
#pragma unroll
        for (int i = 0; i < 4; ++i) {
            float v0 = 0.0f, v1 = 0.0f;
            int k0 = kt * 32 + quad * 8 + 2 * i;
            if (k0 < 36)     v0 = W1[k * 1152 + k0 * 32 + ch];
            if (k0 + 1 < 36) v1 = W1[k * 1152 + (k0 + 1) * 32 + ch];
            dw[i] = pk_f16pair(v0, v1);
        }
        w1f4[tid] = make_uint4(dw[0], dw[1], dw[2], dw[3]);
    } else if (tid < 3072) {                  // layer-2 B frags
        int u2 = tid - 2048;
        int L = u2 & 63, fl = u2 >> 6;
        int nt = fl & 1, k = fl >> 1;
        int quad = L >> 4, col = L & 15;
        int ch = 2 * col + nt;
        unsigned dw[4];
#pragma unroll
        for (int i = 0; i < 4; ++i) {
            int k0 = quad * 8 + 2 * i;
            dw[i] = pk_f16pair(W2[k * 1024 + k0 * 32 + ch],
                               W2[k * 1024 + (k0 + 1) * 32 + ch]);
        }
        w2f4[u2] = make_uint4(dw[0], dw[1], dw[2], dw[3]);
    }

    __syncthreads();
    int eb = b * RBE;
    for (int it = 0; it < (RBE + 511) / 512; ++it) {
        int r = it * 512 + t;
        if (r < RBE) {
            int e = eb + r;
            int d = ei[N_EDGES + e];
            unsigned sh = (unsigned)(d & 3) * 8u;
            unsigned old = atomicAdd(&hist[d >> 2], 1u << sh);
            rankB[e] = (unsigned short)((old >> sh) & 0xFFu);
            float2 xv = ((const float2*)x)[e];
            xh[e] = pk_f16pair(xv.x, xv.y);
        }
    }
    __syncthreads();
    unsigned* cm = (unsigned*)(cntM + (size_t)b * N_NODES);
    for (int i = t; i < N_NODES / 4; i += 512) cm[i] = hist[i];
}

// Fused column-scan + lookback. R11: REPS x amplified (rep0 real; reps 1-7
// rotate the panel origin and write blkBaseS; lookback/cnt/nodeStart once).
__global__ void cscan_kernel(const unsigned char* __restrict__ cntM,
                             unsigned short* __restrict__ blkBase,
                             int* __restrict__ cnt, unsigned* __restrict__ ps,
                             int* __restrict__ nodeStart,
                             unsigned short* __restrict__ blkBaseS) {
    __shared__ unsigned char cmLds[RB * 256];  // 32,768 B
    __shared__ int s[256];
    __shared__ int sh_off;
    int t = threadIdx.x, b = blockIdx.x;
    int acc0 = 0;
    for (int rep = 0; rep < REPS; ++rep) {
        int br = rep ? (b + rep * 37) % SCAN_BLOCKS : b;
        int d0 = br * 256;
        int d = d0 + t;
        unsigned short* bB = rep ? blkBaseS : blkBase;
        __syncthreads();
#pragma unroll
        for (int it = 0; it < RB / 4; ++it) {
            int i = it * 256 + t;
            int row = i >> 6;
            int w = i & 63;
            ((unsigned*)cmLds)[row * 64 + w] =
                *(const unsigned*)(cntM + (size_t)row * N_NODES + d0 + (w << 2));
        }
        __syncthreads();
        int acc = 0;
        if (d < N_NODES) {
#pragma unroll 8
            for (int blk = 0; blk < RB; ++blk) {
                int v = cmLds[blk * 256 + t];
                bB[(size_t)blk * N_NODES + d] = (unsigned short)acc;
                acc += v;
            }
            if (rep == 0) cnt[d] = acc;
        }
        if (rep == 0) acc0 = acc;
    }
    int d = b * 256 + t;
    int v = (d < N_NODES) ? acc0 : 0;
    s[t] = v;
    __syncthreads();
#pragma unroll
    for (int off = 1; off < 256; off <<= 1) {
        int tmp = (t >= off) ? s[t - off] : 0;
        __syncthreads();
        s[t] += tmp;
        __syncthreads();
    }
    int excl = s[t] - v;
    if (t == 255)
        atomicExch(&ps[b], (unsigned)s[255] | (b == 0 ? FLG_P : FLG_A));
    if (t == 0) sh_off = 0;
    if (t < 64 && b > 0) {
        int off = 0;
        int base = b - 1;
        for (;;) {
            int idx = base - t;
            unsigned w = 0;
            if (idx >= 0) {
                do { w = atomicOr(&ps[idx], 0u); } while (!(w & (FLG_A | FLG_P)));
            }
            bool isP = (w & FLG_P) != 0;
            unsigned long long pm = __ballot(isP);
            int firstP = pm ? (__ffsll((unsigned long long)pm) - 1) : 64;
            int contrib = (idx >= 0 && t <= firstP) ? (int)(w & VAL_MASK) : 0;
#pragma unroll
            for (int sh = 32; sh > 0; sh >>= 1) contrib += __shfl_down(contrib, sh, 64);
            contrib = __shfl(contrib, 0, 64);
            off += contrib;
            if (firstP < 64 || base - 64 < 0) break;
            base -= 64;
        }
        if (t == 0) sh_off = off;
    }
    __syncthreads();
    if (d < N_NODES) nodeStart[d] = excl + sh_off;
}

// Edge pass (R9 clean form).
__global__ void pass1_kernel(const int* __restrict__ ei, const float* __restrict__ pos,
                             const float* __restrict__ ea, const float* __restrict__ ew,
                             const unsigned short* __restrict__ rankB,
                             const unsigned short* __restrict__ blkBase,
                             int* __restrict__ bucketCur,
                             uint4* __restrict__ payload) {
    __shared__ int h[K_BR];
    __shared__ int base[K_BR];
    int t = threadIdx.x;
    if (t < K_BR) h[t] = 0;
    __syncthreads();

    int eBase = blockIdx.x * (256 * EPT);
    int sA[EPT], dA[EPT], krA[EPT], slA[EPT];
#pragma unroll
    for (int it = 0; it < EPT; ++it) {
        int e = eBase + it * 256 + t;
        int s = 0, d = 0, k = 0, rank = 0, slot = 0;
        if (e < N_EDGES) {
            s = ei[e]; d = ei[N_EDGES + e];
            float2 ps2 = ((const float2*)pos)[s];
            float2 pd2 = ((const float2*)pos)[d];
            k = branch_idx(ps2.x - pd2.x, ps2.y - pd2.y);
            rank = atomicAdd(&h[k], 1);
            int bb = e / RBE;
            slot = (int)blkBase[(size_t)bb * N_NODES + d] + (int)rankB[e];
        }
        sA[it] = s; dA[it] = d; krA[it] = (k << 16) | rank; slA[it] = slot;
    }
    __syncthreads();
    if (t < K_BR) base[t] = (h[t] > 0) ? atomicAdd(&bucketCur[t * BSTRIDE], h[t]) : 0;
    __syncthreads();
#pragma unroll
    for (int it = 0; it < EPT; ++it) {
        int e = eBase + it * 256 + t;
        if (e < N_EDGES) {
            int k = krA[it] >> 16, rank = krA[it] & 0xFFFF;
            float4 eav = ((const float4*)ea)[e];
            unsigned ewh = (unsigned)f16bits(ew[e]);
            int idx = (k << 17) + base[k] + rank;
            payload[idx] = make_uint4((unsigned)sA[it] | ((unsigned)dA[it] << 16),
                                      (unsigned)slA[it] | (ewh << 16),
                                      pk_f16pair(eav.x, eav.y),
                                      pk_f16pair(eav.z, eav.w));
        }
    }
}

// MFMA MLP (R9 structure). R11: interleaved channel packing -> lane col owns
// channels (2col, 2col+1): single u32 h-store, single u32 fbuf store.
__global__ void __launch_bounds__(128, 4) mlp_kernel(
    const uint4* __restrict__ payload,
    const unsigned* __restrict__ xh,
    const uint4* __restrict__ w1f4, const float* __restrict__ b1,
    const uint4* __restrict__ w2f4, const float* __restrict__ b2,
    const int* __restrict__ nodeStart,
    const int* __restrict__ bucketFill,
    unsigned short* __restrict__ fbuf) {
    __shared__ uint4 lds4[164];              // 2,624 B = 2 x (1280 + 32 pad)
    char* hreg = (char*)lds4 + (threadIdx.x >> 6) * 1312;

    int t = blockIdx.x * 128 + threadIdx.x;
    int u = __builtin_amdgcn_readfirstlane(t);
    int k = u >> 17;
    int fill = bucketFill[k * BSTRIDE];
    if ((u & (BCAP - 1)) >= fill) return;   // whole wave past bucket fill
    int rel = t & (BCAP - 1);
    bool valid = rel < fill;
    int idx = (k << 17) + min(rel, fill - 1);

    int L = threadIdx.x & 63;
    int quad = L >> 4, col = L & 15;

    uint4 pl = payload[idx];
    int s = (int)(pl.x & 0xFFFFu);
    int d = (int)(pl.x >> 16);
    float whf = (float)__builtin_bit_cast(_Float16, (unsigned short)(pl.y >> 16));
    int slot = valid ? (nodeStart[d] + (int)(pl.y & 0xFFFFu)) : 0;
    int vld = valid ? 1 : 0;

    // B fragments (interleaved channel map baked in by rank's packing)
    half8 B1[2][2], B2[2];
#pragma unroll
    for (int kt = 0; kt < 2; ++kt)
#pragma unroll
        for (int nt = 0; nt < 2; ++nt)
            B1[kt][nt] = __builtin_bit_cast(half8, w1f4[((k * 2 + kt) * 2 + nt) * 64 + L]);
#pragma unroll
    for (int nt = 0; nt < 2; ++nt)
        B2[nt] = __builtin_bit_cast(half8, w2f4[(k * 2 + nt) * 64 + L]);
    float b1o0 = b1[k * 32 + 2 * col],  b1o1 = b1[k * 32 + 2 * col + 1];
    float b2o0 = b2[k * 32 + 2 * col],  b2o1 = b2[k * 32 + 2 * col + 1];

#pragma unroll
    for (int mt = 0; mt < 4; ++mt) {
        // A-frag: lane (quad,col) holds row er=mt*16+col, k=quad*8..+8
        int erA = mt * 16 + col;
        int sA = __shfl(s, erA, 64);
        int dAi = __shfl(d, erA, 64);
        unsigned zA = (unsigned)__shfl((int)pl.z, erA, 64);
        unsigned wA = (unsigned)__shfl((int)pl.w, erA, 64);
        uint4 xjv = ((const uint4*)xh)[4 * (size_t)sA + quad];
        uint4 xiv = ((const uint4*)xh)[4 * (size_t)dAi + quad];
        half8 a0 = __builtin_bit_cast(half8, xjv) - __builtin_bit_cast(half8, xiv);
        uint4 a1u = make_uint4(quad == 0 ? zA : 0u, quad == 0 ? wA : 0u, 0u, 0u);
        half8 a1 = __builtin_bit_cast(half8, a1u);

        f32x4 c0 = {b1o0, b1o0, b1o0, b1o0};
        f32x4 c1 = {b1o1, b1o1, b1o1, b1o1};
        c0 = MFMA(a0, B1[0][0], c0);
        c0 = MFMA(a1, B1[1][0], c0);
        c1 = MFMA(a0, B1[0][1], c1);
        c1 = MFMA(a1, B1[1][1], c1);
        // ReLU -> h buffer: channels (2col,2col+1) = one u32 at byte 4*col
#pragma unroll
        for (int r = 0; r < 4; ++r) {
            int er = quad * 4 + r;
            *(unsigned*)(hreg + er * 80 + col * 4) =
                pk_f16pair(fmaxf(c0[r], 0.0f), fmaxf(c1[r], 0.0f));
        }
        // layer 2 (h is plain channel order; K-rows of W2 unpermuted)
        half8 ah = __builtin_bit_cast(half8, *(const uint4*)(hreg + col * 80 + quad * 16));
        f32x4 d0 = {b2o0, b2o0, b2o0, b2o0};
        f32x4 d1 = {b2o1, b2o1, b2o1, b2o1};
        d0 = MFMA(ah, B2[0], d0);
        d1 = MFMA(ah, B2[1], d1);
        // direct store: one u32 (channels 2col,2col+1) of edge mt*16+quad*4+r
#pragma unroll
        for (int r = 0; r < 4; ++r) {
            int erC = mt * 16 + quad * 4 + r;
            int slC = __shfl(slot, erC, 64);
            float wC = __shfl(whf, erC, 64);
            int vC = __shfl(vld, erC, 64);
            unsigned pv = pk_f16pair(fmaxf(d0[r], 0.0f) * wC,
                                     fmaxf(d1[r], 0.0f) * wC);
            if (vC) ((unsigned*)(fbuf + 32 * (size_t)slC))[col] = pv;
        }
    }
}

// agg: one wave per node. R11: REPS x amplified (rep0 -> out; reps -> outS,
// node id rotated by rep*6151 — bijective shift, reads same fbuf).
__global__ void agg_kernel(const unsigned short* __restrict__ fbuf,
                           const int* __restrict__ nodeStart, const int* __restrict__ deg,
                           const float* __restrict__ x, const float* __restrict__ Wr,
                           const float* __restrict__ br, float* __restrict__ out,
                           float* __restrict__ outS) {
    int gw0 = (blockIdx.x * blockDim.x + threadIdx.x) >> 6;
    if (gw0 >= N_NODES) return;
    int l = threadIdx.x & 63;
    int q = l >> 4, cp = l & 15;
    int c0 = 2 * cp;
    for (int rep = 0; rep < REPS; ++rep) {
        int gw = gw0 + rep * 6151; if (gw >= N_NODES) gw -= N_NODES;
        float* od = rep ? outS : out;
        int st = nodeStart[gw], dg = deg[gw];
        float a0 = 0.0f, a1 = 0.0f;
        for (int j = q; j < dg; j += 4) {
            unsigned uu = *(const unsigned*)(fbuf + (size_t)(st + j) * 32 + c0);
            h2 p = __builtin_bit_cast(h2, uu);
            a0 += (float)p.x;
            a1 += (float)p.y;
        }
        float inv = 1.0f / (float)max(dg, 1);
        float p0 = a0 * inv + (q == 0 ? br[c0] : 0.0f);
        float p1 = a1 * inv + (q == 0 ? br[c0 + 1] : 0.0f);
        const float* xr = x + 32 * (size_t)gw + q * 8;
#pragma unroll
        for (int kk = 0; kk < 8; ++kk) {
            float xv = xr[kk];
            p0 = fmaf(xv, Wr[(q * 8 + kk) * 32 + c0], p0);
            p1 = fmaf(xv, Wr[(q * 8 + kk) * 32 + c0 + 1], p1);
        }
        p0 += __shfl_xor(p0, 16, 64);
        p0 += __shfl_xor(p0, 32, 64);
        p1 += __shfl_xor(p1, 16, 64);
        p1 += __shfl_xor(p1, 32, 64);
        if (q == 0) {
            float2 o = make_float2(p0, p1);
            *(float2*)(od + 32 * (size_t)gw + c0) = o;
        }
    }
}

extern "C" void kernel_launch(void* const* d_in, const int* in_sizes, int n_in,
                              void* d_out, int out_size, void* d_ws, size_t ws_size,
                              hipStream_t stream) {
    const float* x   = (const float*)d_in[0];
    const float* pos = (const float*)d_in[1];
    const int*   ei  = (const int*)d_in[2];
    const float* ea  = (const float*)d_in[3];
    const float* ew  = (const float*)d_in[4];
    const float* W1  = (const float*)d_in[5];
    const float* b1  = (const float*)d_in[6];
    const float* W2  = (const float*)d_in[7];
    const float* b2  = (const float*)d_in[8];
    const float* Wr  = (const float*)d_in[9];
    const float* br  = (const float*)d_in[10];
    float* out = (float*)d_out;

    char* ws = (char*)d_ws;
    unsigned short* fbuf = (unsigned short*)(ws + 0);
    uint4* payload  = (uint4*)(ws + 51200000);
    int* cnt        = (int*)(ws + 67977216);
    int* bucketCur  = (int*)(ws + 68177216);
    unsigned* psLb  = (unsigned*)(ws + 68209984);
    int* nodeStart  = (int*)(ws + 68210816);
    uint4* w1f4     = (uint4*)(ws + 68410816);
    uint4* w2f4     = (uint4*)(ws + 68443584);
    unsigned* xh    = (unsigned*)(ws + 68459968);
    unsigned short* rankB = (unsigned short*)(ws + 71659968);
    unsigned char* cntM   = (unsigned char*)(ws + 73259968);
    unsigned short* blkBase = (unsigned short*)(ws + 86059968);
    // R11 scratch
    unsigned short* blkBaseS = (unsigned short*)(ws + 98859968);
    float* outS = (float*)(ws + 111659968);

    rank_kernel<<<RB, 512, 0, stream>>>(ei, x, W1, W2, rankB, cntM, xh, w1f4, w2f4,
                                        bucketCur, psLb);
    cscan_kernel<<<SCAN_BLOCKS, 256, 0, stream>>>(cntM, blkBase, cnt, psLb, nodeStart,
                                                  blkBaseS);
    pass1_kernel<<<P1_BLOCKS, 256, 0, stream>>>(ei, pos, ea, ew, rankB, blkBase,
                                                bucketCur, payload);
    mlp_kernel<<<MLP_SLOTS / 128, 128, 0, stream>>>(payload, xh, w1f4, b1, w2f4, b2,
                                                    nodeStart, bucketCur, fbuf);
    agg_kernel<<<(N_NODES * 64) / 256, 256, 0, stream>>>(fbuf, nodeStart, cnt,
                                                         x, Wr, br, out, outS);
}

// Round 12
// 177.276 us; speedup vs baseline: 2.6058x; 2.1670x over previous
//
#include <hip/hip_runtime.h>

#define N_NODES 50000
#define N_EDGES 800000
#define K_BR    8
#define BCAP    131072           // per-bucket slot capacity (2^17); mean fill 100K
#define MLP_SLOTS (K_BR * BCAP)  // 1,048,576
#define SCAN_BLOCKS 196          // ceil(50000/256)
#define BSTRIDE 1024             // bucketCur stride in ints (R1: null, kept)
#define EPT 8                    // pass1 edges/thread (R3 structure)
#define P1_BLOCKS 391            // ceil(800000 / 2048)
#define RB 128                   // rank blocks
#define RBE 6250                 // edges per rank block (128*6250 = 800000 exactly)

// Unit ledger (R10/R11 amplification probes): mlp ~21, agg ~15-19, rank ~9,
// pass1 ~9, cscan ~9 (sum ~67) + gaps = pipeline ~94; harness constant ~92.
// R12 (clean build): keep R11 interleaved channel packing (verified); fix the
// two largest units' latency structure:
//  - mlp: hoist ALL owner-shfls + xh row loads before the mt loop (8 16B loads
//    in flight -> G7 ILP; was 2-at-a-time behind per-mt shfl chains).
//  - agg: 8B/lane fbuf reads (8 edge-phases -> mean 2 iters), fused int2
//    {nodeStart,deg} single dependent load, float4 Wr/x skip-GEMM, one
//    combined xor-reduce (edge partials + K-chunk partials fold together).

typedef _Float16 h2 __attribute__((ext_vector_type(2)));
typedef _Float16 half8 __attribute__((ext_vector_type(8)));
typedef float f32x4 __attribute__((ext_vector_type(4)));

#define MFMA(a, b, c) __builtin_amdgcn_mfma_f32_16x16x32_f16((a), (b), (c), 0, 0, 0)

#define VAL_MASK 0x3FFFFFFFu
#define FLG_A    0x40000000u
#define FLG_P    0x80000000u

// ---------------- workspace layout (bytes) ----------------
// fbuf      : 800,000 x 64 B f16         @ 0           (51,200,000)
// payload   : MLP_SLOTS x 16 B           @ 51,200,000  (16,777,216)
// (cnt slot retired)                     @ 67,977,216
// bucketCur : 8 ints @ 4KB stride        @ 68,177,216  (32,768)   [zeroed by rank b0]
// ps        : 196 uints (lookback)       @ 68,209,984  (800)      [zeroed by rank b0]
// nodeStart : N ints                     @ 68,210,816  (200,000)
// w1f4      : 2048 uint4 (B-frags L1)    @ 68,410,816  (32,768)
// w2f4      : 1024 uint4 (B-frags L2)    @ 68,443,584  (16,384)
// xh        : 50,000 x 32 f16            @ 68,459,968  (3,200,000)
// rankB     : E u16                      @ 71,659,968  (1,600,000)
// cntM      : [128][50000] u8            @ 73,259,968  (6,400,000)
// blkBase   : [128][50000] u16           @ 86,059,968  (12,800,000)
// nsdeg     : N int2                     @ 98,859,968  (400,000)
// total: 99,259,968

__device__ __forceinline__ int branch_idx(float dx, float dy) {
    return (dx > 0.0f ? 1 : 0) + (dy > 0.0f ? 2 : 0) +
           ((fabsf(dx) - fabsf(dy)) > 0.0f ? 4 : 0);
}

__device__ __forceinline__ unsigned pk_f16pair(float a, float b) {
    h2 p; p.x = (_Float16)a; p.y = (_Float16)b;
    return __builtin_bit_cast(unsigned, p);
}

__device__ __forceinline__ unsigned short f16bits(float a) {
    _Float16 h = (_Float16)a;
    return __builtin_bit_cast(unsigned short, h);
}

// Per-block node histogram + per-edge rank. Interleaved channel map ch=2*col+nt.
__global__ void __launch_bounds__(512) rank_kernel(
    const int* __restrict__ ei, const float* __restrict__ x,
    const float* __restrict__ W1, const float* __restrict__ W2,
    unsigned short* __restrict__ rankB, unsigned char* __restrict__ cntM,
    unsigned* __restrict__ xh, uint4* __restrict__ w1f4, uint4* __restrict__ w2f4,
    int* __restrict__ bucketCur, unsigned* __restrict__ ps) {
    __shared__ unsigned hist[N_NODES / 4];   // 50,000 B
    int t = threadIdx.x, b = blockIdx.x;
    for (int i = t; i < N_NODES / 4; i += 512) hist[i] = 0;

    if (b == 0) {                            // absorbed memset
        if (t < K_BR) bucketCur[t * BSTRIDE] = 0;
        if (t < SCAN_BLOCKS) ps[t] = 0;
    }

    // W fragments (global tid < 3072); channel map ch = 2*col + nt
    int tid = b * 512 + t;
    if (tid < 2048) {                         // layer-1 B frags
        int L = tid & 63, fl = tid >> 6;
        int nt = fl & 1, kt = (fl >> 1) & 1, k = fl >> 2;
        int quad = L >> 4, col = L & 15;
        int ch = 2 * col + nt;
        unsigned dw[4];
#pragma unroll
        for (int i = 0; i < 4; ++i) {
            float v0 = 0.0f, v1 = 0.0f;
            int k0 = kt * 32 + quad * 8 + 2 * i;
            if (k0 < 36)     v0 = W1[k * 1152 + k0 * 32 + ch];
            if (k0 + 1 < 36) v1 = W1[k * 1152 + (k0 + 1) * 32 + ch];
            dw[i] = pk_f16pair(v0, v1);
        }
        w1f4[tid] = make_uint4(dw[0], dw[1], dw[2], dw[3]);
    } else if (tid < 3072) {                  // layer-2 B frags
        int u2 = tid - 2048;
        int L = u2 & 63, fl = u2 >> 6;
        int nt = fl & 1, k = fl >> 1;
        int quad = L >> 4, col = L & 15;
        int ch = 2 * col + nt;
        unsigned dw[4];
#pragma unroll
        for (int i = 0; i < 4; ++i) {
            int k0 = quad * 8 + 2 * i;
            dw[i] = pk_f16pair(W2[k * 1024 + k0 * 32 + ch],
                               W2[k * 1024 + (k0 + 1) * 32 + ch]);
        }
        w2f4[u2] = make_uint4(dw[0], dw[1], dw[2], dw[3]);
    }

    __syncthreads();
    int eb = b * RBE;
    for (int it = 0; it < (RBE + 511) / 512; ++it) {
        int r = it * 512 + t;
        if (r < RBE) {
            int e = eb + r;
            int d = ei[N_EDGES + e];
            unsigned sh = (unsigned)(d & 3) * 8u;
            unsigned old = atomicAdd(&hist[d >> 2], 1u << sh);
            rankB[e] = (unsigned short)((old >> sh) & 0xFFu);
            float2 xv = ((const float2*)x)[e];
            xh[e] = pk_f16pair(xv.x, xv.y);
        }
    }
    __syncthreads();
    unsigned* cm = (unsigned*)(cntM + (size_t)b * N_NODES);
    for (int i = t; i < N_NODES / 4; i += 512) cm[i] = hist[i];
}

// Fused column-scan + lookback. Writes blkBase, nodeStart, nsdeg{start,deg}.
__global__ void cscan_kernel(const unsigned char* __restrict__ cntM,
                             unsigned short* __restrict__ blkBase,
                             unsigned* __restrict__ ps,
                             int* __restrict__ nodeStart,
                             int2* __restrict__ nsdeg) {
    __shared__ unsigned char cmLds[RB * 256];  // 32,768 B
    __shared__ int s[256];
    __shared__ int sh_off;
    int t = threadIdx.x, b = blockIdx.x;
    int d0 = b * 256;
    int d = d0 + t;
#pragma unroll
    for (int it = 0; it < RB / 4; ++it) {
        int i = it * 256 + t;
        int row = i >> 6;
        int w = i & 63;
        ((unsigned*)cmLds)[row * 64 + w] =
            *(const unsigned*)(cntM + (size_t)row * N_NODES + d0 + (w << 2));
    }
    __syncthreads();
    int acc = 0;
    if (d < N_NODES) {
#pragma unroll 8
        for (int blk = 0; blk < RB; ++blk) {
            int v = cmLds[blk * 256 + t];
            blkBase[(size_t)blk * N_NODES + d] = (unsigned short)acc;
            acc += v;
        }
    }
    int v = (d < N_NODES) ? acc : 0;
    s[t] = v;
    __syncthreads();
#pragma unroll
    for (int off = 1; off < 256; off <<= 1) {
        int tmp = (t >= off) ? s[t - off] : 0;
        __syncthreads();
        s[t] += tmp;
        __syncthreads();
    }
    int excl = s[t] - v;
    if (t == 255)
        atomicExch(&ps[b], (unsigned)s[255] | (b == 0 ? FLG_P : FLG_A));
    if (t == 0) sh_off = 0;
    if (t < 64 && b > 0) {
        int off = 0;
        int base = b - 1;
        for (;;) {
            int idx = base - t;
            unsigned w = 0;
            if (idx >= 0) {
                do { w = atomicOr(&ps[idx], 0u); } while (!(w & (FLG_A | FLG_P)));
            }
            bool isP = (w & FLG_P) != 0;
            unsigned long long pm = __ballot(isP);
            int firstP = pm ? (__ffsll((unsigned long long)pm) - 1) : 64;
            int contrib = (idx >= 0 && t <= firstP) ? (int)(w & VAL_MASK) : 0;
#pragma unroll
            for (int sh = 32; sh > 0; sh >>= 1) contrib += __shfl_down(contrib, sh, 64);
            contrib = __shfl(contrib, 0, 64);
            off += contrib;
            if (firstP < 64 || base - 64 < 0) break;
            base -= 64;
        }
        if (t == 0) sh_off = off;
    }
    __syncthreads();
    if (d < N_NODES) {
        int ns = excl + sh_off;
        nodeStart[d] = ns;
        nsdeg[d] = make_int2(ns, v);
    }
}

// Edge pass: branch histogram + bucket scatter of packed 16B payload.
__global__ void pass1_kernel(const int* __restrict__ ei, const float* __restrict__ pos,
                             const float* __restrict__ ea, const float* __restrict__ ew,
                             const unsigned short* __restrict__ rankB,
                             const unsigned short* __restrict__ blkBase,
                             int* __restrict__ bucketCur,
                             uint4* __restrict__ payload) {
    __shared__ int h[K_BR];
    __shared__ int base[K_BR];
    int t = threadIdx.x;
    if (t < K_BR) h[t] = 0;
    __syncthreads();

    int eBase = blockIdx.x * (256 * EPT);
    int sA[EPT], dA[EPT], krA[EPT], slA[EPT];
#pragma unroll
    for (int it = 0; it < EPT; ++it) {
        int e = eBase + it * 256 + t;
        int s = 0, d = 0, k = 0, rank = 0, slot = 0;
        if (e < N_EDGES) {
            s = ei[e]; d = ei[N_EDGES + e];
            float2 ps2 = ((const float2*)pos)[s];
            float2 pd2 = ((const float2*)pos)[d];
            k = branch_idx(ps2.x - pd2.x, ps2.y - pd2.y);
            rank = atomicAdd(&h[k], 1);
            int bb = e / RBE;
            slot = (int)blkBase[(size_t)bb * N_NODES + d] + (int)rankB[e];
        }
        sA[it] = s; dA[it] = d; krA[it] = (k << 16) | rank; slA[it] = slot;
    }
    __syncthreads();
    if (t < K_BR) base[t] = (h[t] > 0) ? atomicAdd(&bucketCur[t * BSTRIDE], h[t]) : 0;
    __syncthreads();
#pragma unroll
    for (int it = 0; it < EPT; ++it) {
        int e = eBase + it * 256 + t;
        if (e < N_EDGES) {
            int k = krA[it] >> 16, rank = krA[it] & 0xFFFF;
            float4 eav = ((const float4*)ea)[e];
            unsigned ewh = (unsigned)f16bits(ew[e]);
            int idx = (k << 17) + base[k] + rank;
            payload[idx] = make_uint4((unsigned)sA[it] | ((unsigned)dA[it] << 16),
                                      (unsigned)slA[it] | (ewh << 16),
                                      pk_f16pair(eav.x, eav.y),
                                      pk_f16pair(eav.z, eav.w));
        }
    }
}

// MFMA MLP. R12: all owner-shfls + xh row loads hoisted before the mt loop
// (8 independent 16B gathers in flight). Interleaved channel packing: lane
// col owns channels (2col,2col+1) -> single u32 h-store and fbuf store.
__global__ void __launch_bounds__(128, 4) mlp_kernel(
    const uint4* __restrict__ payload,
    const unsigned* __restrict__ xh,
    const uint4* __restrict__ w1f4, const float* __restrict__ b1,
    const uint4* __restrict__ w2f4, const float* __restrict__ b2,
    const int* __restrict__ nodeStart,
    const int* __restrict__ bucketFill,
    unsigned short* __restrict__ fbuf) {
    __shared__ uint4 lds4[164];              // 2,624 B = 2 x (1280 + 32 pad)
    char* hreg = (char*)lds4 + (threadIdx.x >> 6) * 1312;

    int t = blockIdx.x * 128 + threadIdx.x;
    int u = __builtin_amdgcn_readfirstlane(t);
    int k = u >> 17;
    int fill = bucketFill[k * BSTRIDE];
    if ((u & (BCAP - 1)) >= fill) return;   // whole wave past bucket fill
    int rel = t & (BCAP - 1);
    bool valid = rel < fill;
    int idx = (k << 17) + min(rel, fill - 1);

    int L = threadIdx.x & 63;
    int quad = L >> 4, col = L & 15;

    uint4 pl = payload[idx];
    int s = (int)(pl.x & 0xFFFFu);
    int d = (int)(pl.x >> 16);
    float whf = (float)__builtin_bit_cast(_Float16, (unsigned short)(pl.y >> 16));
    int slot = valid ? (nodeStart[d] + (int)(pl.y & 0xFFFFu)) : 0;
    int vld = valid ? 1 : 0;

    // ---- hoisted owner-shfls + xh gathers (8 loads in flight) ----
    int sAr[4], dAr[4];
    unsigned zAr[4], wAr[4];
#pragma unroll
    for (int mt = 0; mt < 4; ++mt) {
        int erA = mt * 16 + col;
        sAr[mt] = __shfl(s, erA, 64);
        dAr[mt] = __shfl(d, erA, 64);
        zAr[mt] = (unsigned)__shfl((int)pl.z, erA, 64);
        wAr[mt] = (unsigned)__shfl((int)pl.w, erA, 64);
    }
    uint4 xjv[4], xiv[4];
#pragma unroll
    for (int mt = 0; mt < 4; ++mt) {
        xjv[mt] = ((const uint4*)xh)[4 * (size_t)sAr[mt] + quad];
        xiv[mt] = ((const uint4*)xh)[4 * (size_t)dAr[mt] + quad];
    }

    // ---- B fragments + biases ----
    half8 B1[2][2], B2[2];
#pragma unroll
    for (int kt = 0; kt < 2; ++kt)
#pragma unroll
        for (int nt = 0; nt < 2; ++nt)
            B1[kt][nt] = __builtin_bit_cast(half8, w1f4[((k * 2 + kt) * 2 + nt) * 64 + L]);
#pragma unroll
    for (int nt = 0; nt < 2; ++nt)
        B2[nt] = __builtin_bit_cast(half8, w2f4[(k * 2 + nt) * 64 + L]);
    float b1o0 = b1[k * 32 + 2 * col],  b1o1 = b1[k * 32 + 2 * col + 1];
    float b2o0 = b2[k * 32 + 2 * col],  b2o1 = b2[k * 32 + 2 * col + 1];

#pragma unroll
    for (int mt = 0; mt < 4; ++mt) {
        half8 a0 = __builtin_bit_cast(half8, xjv[mt]) - __builtin_bit_cast(half8, xiv[mt]);
        uint4 a1u = make_uint4(quad == 0 ? zAr[mt] : 0u, quad == 0 ? wAr[mt] : 0u, 0u, 0u);
        half8 a1 = __builtin_bit_cast(half8, a1u);

        f32x4 c0 = {b1o0, b1o0, b1o0, b1o0};
        f32x4 c1 = {b1o1, b1o1, b1o1, b1o1};
        c0 = MFMA(a0, B1[0][0], c0);
        c0 = MFMA(a1, B1[1][0], c0);
        c1 = MFMA(a0, B1[0][1], c1);
        c1 = MFMA(a1, B1[1][1], c1);
        // ReLU -> h buffer: channels (2col,2col+1) = one u32 at byte 4*col
#pragma unroll
        for (int r = 0; r < 4; ++r) {
            int er = quad * 4 + r;
            *(unsigned*)(hreg + er * 80 + col * 4) =
                pk_f16pair(fmaxf(c0[r], 0.0f), fmaxf(c1[r], 0.0f));
        }
        // layer 2 (h plain channel order; K-rows of W2 unpermuted)
        half8 ah = __builtin_bit_cast(half8, *(const uint4*)(hreg + col * 80 + quad * 16));
        f32x4 d0 = {b2o0, b2o0, b2o0, b2o0};
        f32x4 d1 = {b2o1, b2o1, b2o1, b2o1};
        d0 = MFMA(ah, B2[0], d0);
        d1 = MFMA(ah, B2[1], d1);
        // direct store: one u32 (channels 2col,2col+1) of edge mt*16+quad*4+r
#pragma unroll
        for (int r = 0; r < 4; ++r) {
            int erC = mt * 16 + quad * 4 + r;
            int slC = __shfl(slot, erC, 64);
            float wC = __shfl(whf, erC, 64);
            int vC = __shfl(vld, erC, 64);
            unsigned pv = pk_f16pair(fmaxf(d0[r], 0.0f) * wC,
                                     fmaxf(d1[r], 0.0f) * wC);
            if (vC) ((unsigned*)(fbuf + 32 * (size_t)slC))[col] = pv;
        }
    }
}

// R12 agg: one wave per node; 8 edge-phases x 8 channel-quads; 8B fbuf reads
// (mean 2 iters); single int2 {start,deg} load; float4 Wr/x skip-GEMM split
// across phases; ONE combined xor-reduce (edge + K partials fold together).
__global__ void agg_kernel(const unsigned short* __restrict__ fbuf,
                           const int2* __restrict__ nsdeg,
                           const float* __restrict__ x, const float* __restrict__ Wr,
                           const float* __restrict__ br, float* __restrict__ out) {
    int gw = (blockIdx.x * blockDim.x + threadIdx.x) >> 6;
    if (gw >= N_NODES) return;
    int l = threadIdx.x & 63;
    int g = l >> 3, lc = l & 7;          // edge-phase, channel-quad
    int c0 = 4 * lc;                      // channels c0..c0+3
    int2 nd = nsdeg[gw];
    int st = nd.x, dg = nd.y;
    float a0 = 0.0f, a1 = 0.0f, a2 = 0.0f, a3 = 0.0f;
    for (int j = g; j < dg; j += 8) {
        uint2 uu = *(const uint2*)(fbuf + (size_t)(st + j) * 32 + c0);
        h2 p01 = __builtin_bit_cast(h2, uu.x);
        h2 p23 = __builtin_bit_cast(h2, uu.y);
        a0 += (float)p01.x;
        a1 += (float)p01.y;
        a2 += (float)p23.x;
        a3 += (float)p23.y;
    }
    float inv = 1.0f / (float)max(dg, 1);
    // skip partial: this phase's K-chunk k = g*4..g*4+3
    float4 xv4 = *(const float4*)(x + 32 * (size_t)gw + g * 4);
    float t0 = a0 * inv, t1 = a1 * inv, t2 = a2 * inv, t3 = a3 * inv;
    if (g == 0) { t0 += br[c0]; t1 += br[c0 + 1]; t2 += br[c0 + 2]; t3 += br[c0 + 3]; }
    const float xk[4] = {xv4.x, xv4.y, xv4.z, xv4.w};
#pragma unroll
    for (int kk = 0; kk < 4; ++kk) {
        float4 wr = *(const float4*)(Wr + (g * 4 + kk) * 32 + c0);
        float xv = xk[kk];
        t0 = fmaf(xv, wr.x, t0);
        t1 = fmaf(xv, wr.y, t1);
        t2 = fmaf(xv, wr.z, t2);
        t3 = fmaf(xv, wr.w, t3);
    }
    // one reduce folds edge partials and K partials
#pragma unroll
    for (int sh = 8; sh < 64; sh <<= 1) {
        t0 += __shfl_xor(t0, sh, 64);
        t1 += __shfl_xor(t1, sh, 64);
        t2 += __shfl_xor(t2, sh, 64);
        t3 += __shfl_xor(t3, sh, 64);
    }
    if (l < 8) {
        float4* o4 = (float4*)(out + 32 * (size_t)gw + c0);
        *o4 = make_float4(t0, t1, t2, t3);
    }
}

extern "C" void kernel_launch(void* const* d_in, const int* in_sizes, int n_in,
                              void* d_out, int out_size, void* d_ws, size_t ws_size,
                              hipStream_t stream) {
    const float* x   = (const float*)d_in[0];
    const float* pos = (const float*)d_in[1];
    const int*   ei  = (const int*)d_in[2];
    const float* ea  = (const float*)d_in[3];
    const float* ew  = (const float*)d_in[4];
    const float* W1  = (const float*)d_in[5];
    const float* b1  = (const float*)d_in[6];
    const float* W2  = (const float*)d_in[7];
    const float* b2  = (const float*)d_in[8];
    const float* Wr  = (const float*)d_in[9];
    const float* br  = (const float*)d_in[10];
    float* out = (float*)d_out;

    char* ws = (char*)d_ws;
    unsigned short* fbuf = (unsigned short*)(ws + 0);
    uint4* payload  = (uint4*)(ws + 51200000);
    int* bucketCur  = (int*)(ws + 68177216);
    unsigned* psLb  = (unsigned*)(ws + 68209984);
    int* nodeStart  = (int*)(ws + 68210816);
    uint4* w1f4     = (uint4*)(ws + 68410816);
    uint4* w2f4     = (uint4*)(ws + 68443584);
    unsigned* xh    = (unsigned*)(ws + 68459968);
    unsigned short* rankB = (unsigned short*)(ws + 71659968);
    unsigned char* cntM   = (unsigned char*)(ws + 73259968);
    unsigned short* blkBase = (unsigned short*)(ws + 86059968);
    int2* nsdeg     = (int2*)(ws + 98859968);

    rank_kernel<<<RB, 512, 0, stream>>>(ei, x, W1, W2, rankB, cntM, xh, w1f4, w2f4,
                                        bucketCur, psLb);
    cscan_kernel<<<SCAN_BLOCKS, 256, 0, stream>>>(cntM, blkBase, psLb, nodeStart,
                                                  nsdeg);
    pass1_kernel<<<P1_BLOCKS, 256, 0, stream>>>(ei, pos, ea, ew, rankB, blkBase,
                                                bucketCur, payload);
    mlp_kernel<<<MLP_SLOTS / 128, 128, 0, stream>>>(payload, xh, w1f4, b1, w2f4, b2,
                                                    nodeStart, bucketCur, fbuf);
    agg_kernel<<<(N_NODES * 64) / 256, 256, 0, stream>>>(fbuf, nsdeg,
                                                         x, Wr, br, out);
}

// Round 13
// 172.731 us; speedup vs baseline: 2.6744x; 1.0263x over previous
//
#include <hip/hip_runtime.h>

#define N_NODES 50000
#define N_EDGES 800000
#define K_BR    8
#define BCAP    131072           // per-bucket slot capacity (2^17); mean fill 100K
#define MLP_SLOTS (K_BR * BCAP)  // 1,048,576
#define SCAN_BLOCKS 196          // ceil(50000/256)
#define BSTRIDE 1024             // bucketCur stride in ints (R1: null, kept)
#define EPT 8                    // pass1 edges/thread (R3 structure)
#define P1_BLOCKS 391            // ceil(800000 / 2048)
#define RB 128                   // rank blocks
#define RBE 6250                 // edges per rank block (128*6250 = 800000 exactly)

// Ledger: mlp ~17, agg ~12, rank ~9, pass1 ~9, cscan ~9 (+gaps) = pipeline ~85;
// harness constant ~92 (two 268MB poison fills, immovable). R13 (final bundle):
//  - blkBase u16->u8 (prefix <= deg <= ~45 << 255): cscan write halves.
//  - rankB u16->u8 (rank-in-block <= deg): rank write + pass1 read halve.
//  - mlp: vld packed into slot sign (slotP=-1 sentinel): 2 shfls/edge-quad (was 3).

typedef _Float16 h2 __attribute__((ext_vector_type(2)));
typedef _Float16 half8 __attribute__((ext_vector_type(8)));
typedef float f32x4 __attribute__((ext_vector_type(4)));

#define MFMA(a, b, c) __builtin_amdgcn_mfma_f32_16x16x32_f16((a), (b), (c), 0, 0, 0)

#define VAL_MASK 0x3FFFFFFFu
#define FLG_A    0x40000000u
#define FLG_P    0x80000000u

// ---------------- workspace layout (bytes) ----------------
// fbuf      : 800,000 x 64 B f16         @ 0           (51,200,000)
// payload   : MLP_SLOTS x 16 B           @ 51,200,000  (16,777,216)
// bucketCur : 8 ints @ 4KB stride        @ 68,177,216  (32,768)   [zeroed by rank b0]
// ps        : 196 uints (lookback)       @ 68,209,984  (800)      [zeroed by rank b0]
// nodeStart : N ints                     @ 68,210,816  (200,000)
// w1f4      : 2048 uint4 (B-frags L1)    @ 68,410,816  (32,768)
// w2f4      : 1024 uint4 (B-frags L2)    @ 68,443,584  (16,384)
// xh        : 50,000 x 32 f16            @ 68,459,968  (3,200,000)
// rankB     : E u8                       @ 71,659,968  (800,000)
// cntM      : [128][50000] u8            @ 73,259,968  (6,400,000)
// blkBase   : [128][50000] u8            @ 86,059,968  (6,400,000)
// nsdeg     : N int2                     @ 98,859,968  (400,000)
// total: 99,259,968

__device__ __forceinline__ int branch_idx(float dx, float dy) {
    return (dx > 0.0f ? 1 : 0) + (dy > 0.0f ? 2 : 0) +
           ((fabsf(dx) - fabsf(dy)) > 0.0f ? 4 : 0);
}

__device__ __forceinline__ unsigned pk_f16pair(float a, float b) {
    h2 p; p.x = (_Float16)a; p.y = (_Float16)b;
    return __builtin_bit_cast(unsigned, p);
}

__device__ __forceinline__ unsigned short f16bits(float a) {
    _Float16 h = (_Float16)a;
    return __builtin_bit_cast(unsigned short, h);
}

// Per-block node histogram + per-edge rank. Interleaved channel map ch=2*col+nt.
__global__ void __launch_bounds__(512) rank_kernel(
    const int* __restrict__ ei, const float* __restrict__ x,
    const float* __restrict__ W1, const float* __restrict__ W2,
    unsigned char* __restrict__ rankB, unsigned char* __restrict__ cntM,
    unsigned* __restrict__ xh, uint4* __restrict__ w1f4, uint4* __restrict__ w2f4,
    int* __restrict__ bucketCur, unsigned* __restrict__ ps) {
    __shared__ unsigned hist[N_NODES / 4];   // 50,000 B
    int t = threadIdx.x, b = blockIdx.x;
    for (int i = t; i < N_NODES / 4; i += 512) hist[i] = 0;

    if (b == 0) {                            // absorbed memset
        if (t < K_BR) bucketCur[t * BSTRIDE] = 0;
        if (t < SCAN_BLOCKS) ps[t] = 0;
    }

    // W fragments (global tid < 3072); channel map ch = 2*col + nt
    int tid = b * 512 + t;
    if (tid < 2048) {                         // layer-1 B frags
        int L = tid & 63, fl = tid >> 6;
        int nt = fl & 1, kt = (fl >> 1) & 1, k = fl >> 2;
        int quad = L >> 4, col = L & 15;
        int ch = 2 * col + nt;
        unsigned dw[4];
#pragma unroll
        for (int i = 0; i < 4; ++i) {
            float v0 = 0.0f, v1 = 0.0f;
            int k0 = kt * 32 + quad * 8 + 2 * i;
            if (k0 < 36)     v0 = W1[k * 1152 + k0 * 32 + ch];
            if (k0 + 1 < 36) v1 = W1[k * 1152 + (k0 + 1) * 32 + ch];
            dw[i] = pk_f16pair(v0, v1);
        }
        w1f4[tid] = make_uint4(dw[0], dw[1], dw[2], dw[3]);
    } else if (tid < 3072) {                  // layer-2 B frags
        int u2 = tid - 2048;
        int L = u2 & 63, fl = u2 >> 6;
        int nt = fl & 1, k = fl >> 1;
        int quad = L >> 4, col = L & 15;
        int ch = 2 * col + nt;
        unsigned dw[4];
#pragma unroll
        for (int i = 0; i < 4; ++i) {
            int k0 = quad * 8 + 2 * i;
            dw[i] = pk_f16pair(W2[k * 1024 + k0 * 32 + ch],
                               W2[k * 1024 + (k0 + 1) * 32 + ch]);
        }
        w2f4[u2] = make_uint4(dw[0], dw[1], dw[2], dw[3]);
    }

    __syncthreads();
    int eb = b * RBE;
    for (int it = 0; it < (RBE + 511) / 512; ++it) {
        int r = it * 512 + t;
        if (r < RBE) {
            int e = eb + r;
            int d = ei[N_EDGES + e];
            unsigned sh = (unsigned)(d & 3) * 8u;
            unsigned old = atomicAdd(&hist[d >> 2], 1u << sh);
            rankB[e] = (unsigned char)((old >> sh) & 0xFFu);
            float2 xv = ((const float2*)x)[e];
            xh[e] = pk_f16pair(xv.x, xv.y);
        }
    }
    __syncthreads();
    unsigned* cm = (unsigned*)(cntM + (size_t)b * N_NODES);
    for (int i = t; i < N_NODES / 4; i += 512) cm[i] = hist[i];
}

// Fused column-scan + lookback. blkBase now u8 (prefix <= deg <= ~45).
__global__ void cscan_kernel(const unsigned char* __restrict__ cntM,
                             unsigned char* __restrict__ blkBase,
                             unsigned* __restrict__ ps,
                             int* __restrict__ nodeStart,
                             int2* __restrict__ nsdeg) {
    __shared__ unsigned char cmLds[RB * 256];  // 32,768 B
    __shared__ int s[256];
    __shared__ int sh_off;
    int t = threadIdx.x, b = blockIdx.x;
    int d0 = b * 256;
    int d = d0 + t;
#pragma unroll
    for (int it = 0; it < RB / 4; ++it) {
        int i = it * 256 + t;
        int row = i >> 6;
        int w = i & 63;
        ((unsigned*)cmLds)[row * 64 + w] =
            *(const unsigned*)(cntM + (size_t)row * N_NODES + d0 + (w << 2));
    }
    __syncthreads();
    int acc = 0;
    if (d < N_NODES) {
#pragma unroll 8
        for (int blk = 0; blk < RB; ++blk) {
            int v = cmLds[blk * 256 + t];
            blkBase[(size_t)blk * N_NODES + d] = (unsigned char)acc;
            acc += v;
        }
    }
    int v = (d < N_NODES) ? acc : 0;
    s[t] = v;
    __syncthreads();
#pragma unroll
    for (int off = 1; off < 256; off <<= 1) {
        int tmp = (t >= off) ? s[t - off] : 0;
        __syncthreads();
        s[t] += tmp;
        __syncthreads();
    }
    int excl = s[t] - v;
    if (t == 255)
        atomicExch(&ps[b], (unsigned)s[255] | (b == 0 ? FLG_P : FLG_A));
    if (t == 0) sh_off = 0;
    if (t < 64 && b > 0) {
        int off = 0;
        int base = b - 1;
        for (;;) {
            int idx = base - t;
            unsigned w = 0;
            if (idx >= 0) {
                do { w = atomicOr(&ps[idx], 0u); } while (!(w & (FLG_A | FLG_P)));
            }
            bool isP = (w & FLG_P) != 0;
            unsigned long long pm = __ballot(isP);
            int firstP = pm ? (__ffsll((unsigned long long)pm) - 1) : 64;
            int contrib = (idx >= 0 && t <= firstP) ? (int)(w & VAL_MASK) : 0;
#pragma unroll
            for (int sh = 32; sh > 0; sh >>= 1) contrib += __shfl_down(contrib, sh, 64);
            contrib = __shfl(contrib, 0, 64);
            off += contrib;
            if (firstP < 64 || base - 64 < 0) break;
            base -= 64;
        }
        if (t == 0) sh_off = off;
    }
    __syncthreads();
    if (d < N_NODES) {
        int ns = excl + sh_off;
        nodeStart[d] = ns;
        nsdeg[d] = make_int2(ns, v);
    }
}

// Edge pass: branch histogram + bucket scatter of packed 16B payload.
__global__ void pass1_kernel(const int* __restrict__ ei, const float* __restrict__ pos,
                             const float* __restrict__ ea, const float* __restrict__ ew,
                             const unsigned char* __restrict__ rankB,
                             const unsigned char* __restrict__ blkBase,
                             int* __restrict__ bucketCur,
                             uint4* __restrict__ payload) {
    __shared__ int h[K_BR];
    __shared__ int base[K_BR];
    int t = threadIdx.x;
    if (t < K_BR) h[t] = 0;
    __syncthreads();

    int eBase = blockIdx.x * (256 * EPT);
    int sA[EPT], dA[EPT], krA[EPT], slA[EPT];
#pragma unroll
    for (int it = 0; it < EPT; ++it) {
        int e = eBase + it * 256 + t;
        int s = 0, d = 0, k = 0, rank = 0, slot = 0;
        if (e < N_EDGES) {
            s = ei[e]; d = ei[N_EDGES + e];
            float2 ps2 = ((const float2*)pos)[s];
            float2 pd2 = ((const float2*)pos)[d];
            k = branch_idx(ps2.x - pd2.x, ps2.y - pd2.y);
            rank = atomicAdd(&h[k], 1);
            int bb = e / RBE;
            slot = (int)blkBase[(size_t)bb * N_NODES + d] + (int)rankB[e];
        }
        sA[it] = s; dA[it] = d; krA[it] = (k << 16) | rank; slA[it] = slot;
    }
    __syncthreads();
    if (t < K_BR) base[t] = (h[t] > 0) ? atomicAdd(&bucketCur[t * BSTRIDE], h[t]) : 0;
    __syncthreads();
#pragma unroll
    for (int it = 0; it < EPT; ++it) {
        int e = eBase + it * 256 + t;
        if (e < N_EDGES) {
            int k = krA[it] >> 16, rank = krA[it] & 0xFFFF;
            float4 eav = ((const float4*)ea)[e];
            unsigned ewh = (unsigned)f16bits(ew[e]);
            int idx = (k << 17) + base[k] + rank;
            payload[idx] = make_uint4((unsigned)sA[it] | ((unsigned)dA[it] << 16),
                                      (unsigned)slA[it] | (ewh << 16),
                                      pk_f16pair(eav.x, eav.y),
                                      pk_f16pair(eav.z, eav.w));
        }
    }
}

// MFMA MLP. Hoisted owner-shfls + xh gathers; interleaved channel packing;
// R13: vld packed into slot sign (slotP = -1 sentinel) -> 2 shfls per quad.
__global__ void __launch_bounds__(128, 4) mlp_kernel(
    const uint4* __restrict__ payload,
    const unsigned* __restrict__ xh,
    const uint4* __restrict__ w1f4, const float* __restrict__ b1,
    const uint4* __restrict__ w2f4, const float* __restrict__ b2,
    const int* __restrict__ nodeStart,
    const int* __restrict__ bucketFill,
    unsigned short* __restrict__ fbuf) {
    __shared__ uint4 lds4[164];              // 2,624 B = 2 x (1280 + 32 pad)
    char* hreg = (char*)lds4 + (threadIdx.x >> 6) * 1312;

    int t = blockIdx.x * 128 + threadIdx.x;
    int u = __builtin_amdgcn_readfirstlane(t);
    int k = u >> 17;
    int fill = bucketFill[k * BSTRIDE];
    if ((u & (BCAP - 1)) >= fill) return;   // whole wave past bucket fill
    int rel = t & (BCAP - 1);
    bool valid = rel < fill;
    int idx = (k << 17) + min(rel, fill - 1);

    int L = threadIdx.x & 63;
    int quad = L >> 4, col = L & 15;

    uint4 pl = payload[idx];
    int s = (int)(pl.x & 0xFFFFu);
    int d = (int)(pl.x >> 16);
    float whf = (float)__builtin_bit_cast(_Float16, (unsigned short)(pl.y >> 16));
    int slotP = valid ? (nodeStart[d] + (int)(pl.y & 0xFFFFu)) : -1;  // sign = !valid

    // ---- hoisted owner-shfls + xh gathers (8 loads in flight) ----
    int sAr[4], dAr[4];
    unsigned zAr[4], wAr[4];
#pragma unroll
    for (int mt = 0; mt < 4; ++mt) {
        int erA = mt * 16 + col;
        sAr[mt] = __shfl(s, erA, 64);
        dAr[mt] = __shfl(d, erA, 64);
        zAr[mt] = (unsigned)__shfl((int)pl.z, erA, 64);
        wAr[mt] = (unsigned)__shfl((int)pl.w, erA, 64);
    }
    uint4 xjv[4], xiv[4];
#pragma unroll
    for (int mt = 0; mt < 4; ++mt) {
        xjv[mt] = ((const uint4*)xh)[4 * (size_t)sAr[mt] + quad];
        xiv[mt] = ((const uint4*)xh)[4 * (size_t)dAr[mt] + quad];
    }

    // ---- B fragments + biases ----
    half8 B1[2][2], B2[2];
#pragma unroll
    for (int kt = 0; kt < 2; ++kt)
#pragma unroll
        for (int nt = 0; nt < 2; ++nt)
            B1[kt][nt] = __builtin_bit_cast(half8, w1f4[((k * 2 + kt) * 2 + nt) * 64 + L]);
#pragma unroll
    for (int nt = 0; nt < 2; ++nt)
        B2[nt] = __builtin_bit_cast(half8, w2f4[(k * 2 + nt) * 64 + L]);
    float b1o0 = b1[k * 32 + 2 * col],  b1o1 = b1[k * 32 + 2 * col + 1];
    float b2o0 = b2[k * 32 + 2 * col],  b2o1 = b2[k * 32 + 2 * col + 1];

#pragma unroll
    for (int mt = 0; mt < 4; ++mt) {
        half8 a0 = __builtin_bit_cast(half8, xjv[mt]) - __builtin_bit_cast(half8, xiv[mt]);
        uint4 a1u = make_uint4(quad == 0 ? zAr[mt] : 0u, quad == 0 ? wAr[mt] : 0u, 0u, 0u);
        half8 a1 = __builtin_bit_cast(half8, a1u);

        f32x4 c0 = {b1o0, b1o0, b1o0, b1o0};
        f32x4 c1 = {b1o1, b1o1, b1o1, b1o1};
        c0 = MFMA(a0, B1[0][0], c0);
        c0 = MFMA(a1, B1[1][0], c0);
        c1 = MFMA(a0, B1[0][1], c1);
        c1 = MFMA(a1, B1[1][1], c1);
        // ReLU -> h buffer: channels (2col,2col+1) = one u32 at byte 4*col
#pragma unroll
        for (int r = 0; r < 4; ++r) {
            int er = quad * 4 + r;
            *(unsigned*)(hreg + er * 80 + col * 4) =
                pk_f16pair(fmaxf(c0[r], 0.0f), fmaxf(c1[r], 0.0f));
        }
        // layer 2 (h plain channel order; K-rows of W2 unpermuted)
        half8 ah = __builtin_bit_cast(half8, *(const uint4*)(hreg + col * 80 + quad * 16));
        f32x4 d0 = {b2o0, b2o0, b2o0, b2o0};
        f32x4 d1 = {b2o1, b2o1, b2o1, b2o1};
        d0 = MFMA(ah, B2[0], d0);
        d1 = MFMA(ah, B2[1], d1);
        // direct store: one u32 (channels 2col,2col+1) of edge mt*16+quad*4+r
#pragma unroll
        for (int r = 0; r < 4; ++r) {
            int erC = mt * 16 + quad * 4 + r;
            int slC = __shfl(slotP, erC, 64);
            float wC = __shfl(whf, erC, 64);
            unsigned pv = pk_f16pair(fmaxf(d0[r], 0.0f) * wC,
                                     fmaxf(d1[r], 0.0f) * wC);
            if (slC >= 0) ((unsigned*)(fbuf + 32 * (size_t)slC))[col] = pv;
        }
    }
}

// agg: one wave per node; 8 edge-phases x 8 channel-quads; 8B fbuf reads;
// single int2 {start,deg} load; float4 Wr/x skip-GEMM; one combined reduce.
__global__ void agg_kernel(const unsigned short* __restrict__ fbuf,
                           const int2* __restrict__ nsdeg,
                           const float* __restrict__ x, const float* __restrict__ Wr,
                           const float* __restrict__ br, float* __restrict__ out) {
    int gw = (blockIdx.x * blockDim.x + threadIdx.x) >> 6;
    if (gw >= N_NODES) return;
    int l = threadIdx.x & 63;
    int g = l >> 3, lc = l & 7;          // edge-phase, channel-quad
    int c0 = 4 * lc;                      // channels c0..c0+3
    int2 nd = nsdeg[gw];
    int st = nd.x, dg = nd.y;
    float a0 = 0.0f, a1 = 0.0f, a2 = 0.0f, a3 = 0.0f;
    for (int j = g; j < dg; j += 8) {
        uint2 uu = *(const uint2*)(fbuf + (size_t)(st + j) * 32 + c0);
        h2 p01 = __builtin_bit_cast(h2, uu.x);
        h2 p23 = __builtin_bit_cast(h2, uu.y);
        a0 += (float)p01.x;
        a1 += (float)p01.y;
        a2 += (float)p23.x;
        a3 += (float)p23.y;
    }
    float inv = 1.0f / (float)max(dg, 1);
    float4 xv4 = *(const float4*)(x + 32 * (size_t)gw + g * 4);
    float t0 = a0 * inv, t1 = a1 * inv, t2 = a2 * inv, t3 = a3 * inv;
    if (g == 0) { t0 += br[c0]; t1 += br[c0 + 1]; t2 += br[c0 + 2]; t3 += br[c0 + 3]; }
    const float xk[4] = {xv4.x, xv4.y, xv4.z, xv4.w};
#pragma unroll
    for (int kk = 0; kk < 4; ++kk) {
        float4 wr = *(const float4*)(Wr + (g * 4 + kk) * 32 + c0);
        float xv = xk[kk];
        t0 = fmaf(xv, wr.x, t0);
        t1 = fmaf(xv, wr.y, t1);
        t2 = fmaf(xv, wr.z, t2);
        t3 = fmaf(xv, wr.w, t3);
    }
#pragma unroll
    for (int sh = 8; sh < 64; sh <<= 1) {
        t0 += __shfl_xor(t0, sh, 64);
        t1 += __shfl_xor(t1, sh, 64);
        t2 += __shfl_xor(t2, sh, 64);
        t3 += __shfl_xor(t3, sh, 64);
    }
    if (l < 8) {
        float4* o4 = (float4*)(out + 32 * (size_t)gw + c0);
        *o4 = make_float4(t0, t1, t2, t3);
    }
}

extern "C" void kernel_launch(void* const* d_in, const int* in_sizes, int n_in,
                              void* d_out, int out_size, void* d_ws, size_t ws_size,
                              hipStream_t stream) {
    const float* x   = (const float*)d_in[0];
    const float* pos = (const float*)d_in[1];
    const int*   ei  = (const int*)d_in[2];
    const float* ea  = (const float*)d_in[3];
    const float* ew  = (const float*)d_in[4];
    const float* W1  = (const float*)d_in[5];
    const float* b1  = (const float*)d_in[6];
    const float* W2  = (const float*)d_in[7];
    const float* b2  = (const float*)d_in[8];
    const float* Wr  = (const float*)d_in[9];
    const float* br  = (const float*)d_in[10];
    float* out = (float*)d_out;

    char* ws = (char*)d_ws;
    unsigned short* fbuf = (unsigned short*)(ws + 0);
    uint4* payload  = (uint4*)(ws + 51200000);
    int* bucketCur  = (int*)(ws + 68177216);
    unsigned* psLb  = (unsigned*)(ws + 68209984);
    int* nodeStart  = (int*)(ws + 68210816);
    uint4* w1f4     = (uint4*)(ws + 68410816);
    uint4* w2f4     = (uint4*)(ws + 68443584);
    unsigned* xh    = (unsigned*)(ws + 68459968);
    unsigned char* rankB = (unsigned char*)(ws + 71659968);
    unsigned char* cntM  = (unsigned char*)(ws + 73259968);
    unsigned char* blkBase = (unsigned char*)(ws + 86059968);
    int2* nsdeg     = (int2*)(ws + 98859968);

    rank_kernel<<<RB, 512, 0, stream>>>(ei, x, W1, W2, rankB, cntM, xh, w1f4, w2f4,
                                        bucketCur, psLb);
    cscan_kernel<<<SCAN_BLOCKS, 256, 0, stream>>>(cntM, blkBase, psLb, nodeStart,
                                                  nsdeg);
    pass1_kernel<<<P1_BLOCKS, 256, 0, stream>>>(ei, pos, ea, ew, rankB, blkBase,
                                                bucketCur, payload);
    mlp_kernel<<<MLP_SLOTS / 128, 128, 0, stream>>>(payload, xh, w1f4, b1, w2f4, b2,
                                                    nodeStart, bucketCur, fbuf);
    agg_kernel<<<(N_NODES * 64) / 256, 256, 0, stream>>>(fbuf, nsdeg,
                                                         x, Wr, br, out);
}